// Round 5
// baseline (20984.810 us; speedup 1.0000x reference)
//
#include <hip/hip_runtime.h>

#define Tt  512
#define NG  32     // row groups (8 rows each)
#define RPG 8

// ws float offsets:
//  hg   [2][2][256][128]  h for layers 0,1 (consumed by inp), slot = t&1
//  h2f  [256][128]        final h of layer 2
//  xg   [2][2][256][512]  input-gate contributions for layers 1,2, slot = t&1
//  flags (unsigned): hflag[3][32] @ +0, xflag[2][32][2] @ +96  (224 total)
#define OFF_HG  0
#define OFF_H2  131072
#define OFF_XG  163840
#define OFF_FLG 688128
// total 688352 floats = 2.75 MB

__device__ __forceinline__ float sigm(float v) { return 1.f / (1.f + __expf(-v)); }

__device__ __forceinline__ void wait_ge(unsigned* p, unsigned tgt) {
    while (__hip_atomic_load(p, __ATOMIC_RELAXED, __HIP_MEMORY_SCOPE_AGENT) < tgt)
        __builtin_amdgcn_s_sleep(2);
}

__global__ void zero_flags(float* ws) {
    if (threadIdx.x < 224) ((unsigned*)(ws + OFF_FLG))[threadIdx.x] = 0u;
}

__global__ __launch_bounds__(1024, 1) void lstm_persistent(
    const float* __restrict__ x,
    const float* __restrict__ Wih0, const float* __restrict__ Whh0,
    const float* __restrict__ bih0, const float* __restrict__ bhh0,
    const float* __restrict__ Wih1, const float* __restrict__ Whh1,
    const float* __restrict__ bih1, const float* __restrict__ bhh1,
    const float* __restrict__ Wih2, const float* __restrict__ Whh2,
    const float* __restrict__ bih2, const float* __restrict__ bhh2,
    float* __restrict__ ws)
{
    unsigned* flg = (unsigned*)(ws + OFF_FLG);
    const int bid = blockIdx.x, tid = threadIdx.x;

    if (bid < 96) {
        // ---------------- recurrent block: (layer l, row-group g) ----------------
        const int l = bid >> 5, g = bid & 31, r0 = g * RPG;
        const float* Wih = (l == 0) ? Wih0 : (l == 1) ? Wih1 : Wih2;
        const float* Whh = (l == 0) ? Whh0 : (l == 1) ? Whh1 : Whh2;
        const float* bih = (l == 0) ? bih0 : (l == 1) ? bih1 : bih2;
        const float* bhh = (l == 0) ? bhh0 : (l == 1) ? bhh1 : bhh2;

        const int wv = tid >> 6, ln = tid & 63;
        const int c  = wv * 32 + (ln & 31);   // gate column 0..511
        const int kh = ln >> 5;               // k-half 0/1

        // Whh column c, k in [kh*64, kh*64+64) -> registers (contiguous in memory)
        float w[64];
        {
            const float* src = Whh + (size_t)c * 128 + kh * 64;
#pragma unroll
            for (int j4 = 0; j4 < 16; j4++) {
                float4 v = *(const float4*)(src + 4 * j4);
                w[4*j4] = v.x; w[4*j4+1] = v.y; w[4*j4+2] = v.z; w[4*j4+3] = v.w;
            }
        }
        float wih0[8];
        if (l == 0) {
#pragma unroll
            for (int i = 0; i < 8; i++) wih0[i] = (kh == 0) ? Wih[c * 8 + i] : 0.f;
        }

        // cell mapping: 1 cell per thread
        const int cr = tid >> 7, chc = tid & 127;
        float b4[4];
#pragma unroll
        for (int q = 0; q < 4; q++) b4[q] = bih[q * 128 + chc] + bhh[q * 128 + chc];
        float cst = 0.f;

        __shared__ float sH[2][RPG][128];
        __shared__ float sG[RPG][512];
        __shared__ float sX[RPG][8];

        unsigned* hf_own = &flg[l * 32 + g];
        unsigned* xf_in0 = &flg[96 + (l - 1) * 64 + g * 2 + 0];   // valid if l>0
        unsigned* xf_in1 = &flg[96 + (l - 1) * 64 + g * 2 + 1];
        unsigned* xf_bp0 = &flg[96 + l * 64 + g * 2 + 0];         // inp(l+1), valid if l<2
        unsigned* xf_bp1 = &flg[96 + l * 64 + g * 2 + 1];

        for (int t = 0; t < Tt; ++t) {
            if (tid == 0) {
                if (l > 0) { wait_ge(xf_in0, t + 1); wait_ge(xf_in1, t + 1); }
                if (l < 2 && t >= 2) { wait_ge(xf_bp0, t - 1); wait_ge(xf_bp1, t - 1); }
                (void)__hip_atomic_load(hf_own, __ATOMIC_ACQUIRE, __HIP_MEMORY_SCOPE_AGENT);
            }
            __syncthreads();

            float xg4[4] = {0.f, 0.f, 0.f, 0.f};
            if (l > 0) {
                // issue early; consumed at cell stage (latency hidden by GEMM)
                const int xb = OFF_XG + (((l - 1) * 2 + (t & 1)) * 256 + (r0 + cr)) * 512 + chc;
#pragma unroll
                for (int q = 0; q < 4; q++)
                    xg4[q] = __hip_atomic_load(ws + xb + q * 128, __ATOMIC_RELAXED, __HIP_MEMORY_SCOPE_AGENT);
            } else {
                if (tid < 64) sX[tid >> 3][tid & 7] = x[(size_t)(r0 + (tid >> 3)) * 4096 + t * 8 + (tid & 7)];
                __syncthreads();   // block-uniform (all l==0 blocks)
            }

            float acc[8] = {0.f,0.f,0.f,0.f,0.f,0.f,0.f,0.f};
            if (t > 0) {
                const float* A = &sH[(t - 1) & 1][0][0] + kh * 64;
#pragma unroll
                for (int j4 = 0; j4 < 16; j4++) {
#pragma unroll
                    for (int r = 0; r < 8; r++) {
                        float4 a = *(const float4*)(A + r * 128 + 4 * j4);
                        acc[r] += a.x * w[4*j4] + a.y * w[4*j4+1] + a.z * w[4*j4+2] + a.w * w[4*j4+3];
                    }
                }
            }
            if (l == 0 && kh == 0) {
#pragma unroll
                for (int i = 0; i < 8; i++)
#pragma unroll
                    for (int r = 0; r < 8; r++) acc[r] += sX[r][i] * wih0[i];
            }
#pragma unroll
            for (int r = 0; r < 8; r++) acc[r] += __shfl_xor(acc[r], 32);
            if (ln < 32) {
#pragma unroll
                for (int r = 0; r < 8; r++) sG[r][c] = acc[r];
            }
            __syncthreads();

            // ---- cell update (c-state in regs, h stays in LDS) ----
            float gi = sG[cr][chc]       + xg4[0] + b4[0];
            float gf = sG[cr][128 + chc] + xg4[1] + b4[1];
            float gg = sG[cr][256 + chc] + xg4[2] + b4[2];
            float go = sG[cr][384 + chc] + xg4[3] + b4[3];
            float cn = sigm(gf) * cst + sigm(gi) * tanhf(gg);
            cst = cn;
            float h = sigm(go) * tanhf(cn);
            sH[t & 1][cr][chc] = h;
            if (l < 2)
                __hip_atomic_store(ws + OFF_HG + ((l * 2 + (t & 1)) * 256 + (r0 + cr)) * 128 + chc,
                                   h, __ATOMIC_RELAXED, __HIP_MEMORY_SCOPE_AGENT);
            else if (t == Tt - 1)
                ws[OFF_H2 + (r0 + cr) * 128 + chc] = h;
            __syncthreads();   // drains vmem (atomic stores) + sH/sG reuse safety
            if (tid == 0)
                __hip_atomic_store(hf_own, (unsigned)(t + 1), __ATOMIC_RELEASE, __HIP_MEMORY_SCOPE_AGENT);
        }
    } else {
        // ---------------- input-GEMM block: (layer l in {1,2}, group g, col-half) ----------------
        const int e = bid - 96;
        const int l = 1 + (e >> 6);
        const int half = (e >> 5) & 1;
        const int g = e & 31, r0 = g * RPG;
        const float* Wih = (l == 1) ? Wih1 : Wih2;

        const int wv = tid >> 6, ln = tid & 63;
        const int cl = wv * 16 + (ln & 15);   // 0..255
        const int kq = ln >> 4;               // 0..3
        const int gc = half * 256 + cl;       // gate column 0..511

        float w[32];
        {
            const float* src = Wih + (size_t)gc * 128 + kq * 32;
#pragma unroll
            for (int j4 = 0; j4 < 8; j4++) {
                float4 v = *(const float4*)(src + 4 * j4);
                w[4*j4] = v.x; w[4*j4+1] = v.y; w[4*j4+2] = v.z; w[4*j4+3] = v.w;
            }
        }

        __shared__ float sH[RPG][128];
        unsigned* hf_in  = &flg[(l - 1) * 32 + g];
        unsigned* hf_bp  = &flg[l * 32 + g];
        unsigned* xf_own = &flg[96 + (l - 1) * 64 + g * 2 + half];
        const int sr = tid >> 7, shc = tid & 127;

        for (int t = 0; t < Tt; ++t) {
            if (tid == 0) {
                wait_ge(hf_in, t + 1);
                if (t >= 2) wait_ge(hf_bp, t - 1);
                (void)__hip_atomic_load(hf_in, __ATOMIC_ACQUIRE, __HIP_MEMORY_SCOPE_AGENT);
            }
            __syncthreads();
            sH[sr][shc] = __hip_atomic_load(
                ws + OFF_HG + (((l - 1) * 2 + (t & 1)) * 256 + (r0 + sr)) * 128 + shc,
                __ATOMIC_RELAXED, __HIP_MEMORY_SCOPE_AGENT);
            __syncthreads();

            float acc[8] = {0.f,0.f,0.f,0.f,0.f,0.f,0.f,0.f};
#pragma unroll
            for (int j4 = 0; j4 < 8; j4++) {
#pragma unroll
                for (int r = 0; r < 8; r++) {
                    float4 a = *(const float4*)(&sH[r][kq * 32 + 4 * j4]);
                    acc[r] += a.x * w[4*j4] + a.y * w[4*j4+1] + a.z * w[4*j4+2] + a.w * w[4*j4+3];
                }
            }
#pragma unroll
            for (int r = 0; r < 8; r++) {
                acc[r] += __shfl_xor(acc[r], 16);
                acc[r] += __shfl_xor(acc[r], 32);
            }
            if (kq == 0) {
                const int xb = OFF_XG + ((l - 1) * 2 + (t & 1)) * 131072;
#pragma unroll
                for (int r = 0; r < 8; r++)
                    __hip_atomic_store(ws + xb + (r0 + r) * 512 + gc, acc[r],
                                       __ATOMIC_RELAXED, __HIP_MEMORY_SCOPE_AGENT);
            }
            __syncthreads();   // drain stores before flag
            if (tid == 0)
                __hip_atomic_store(xf_own, (unsigned)(t + 1), __ATOMIC_RELEASE, __HIP_MEMORY_SCOPE_AGENT);
        }
    }
}

__global__ void fc_kernel(const float* __restrict__ ws, const float* __restrict__ Wfc,
                          const float* __restrict__ bfc, float* __restrict__ out)
{
    const float* h2 = ws + OFF_H2;
    int b = threadIdx.x;   // 256 threads
    float a0 = bfc[0], a1 = bfc[1], a2 = bfc[2];
    for (int k = 0; k < 128; k++) {
        float h = h2[b * 128 + k];
        a0 += h * Wfc[0 * 128 + k];
        a1 += h * Wfc[1 * 128 + k];
        a2 += h * Wfc[2 * 128 + k];
    }
    out[b * 3 + 0] = a0;
    out[b * 3 + 1] = a1;
    out[b * 3 + 2] = a2;
}

extern "C" void kernel_launch(void* const* d_in, const int* in_sizes, int n_in,
                              void* d_out, int out_size, void* d_ws, size_t ws_size,
                              hipStream_t stream)
{
    const float* x = (const float*)d_in[0];
    float* ws = (float*)d_ws;

    zero_flags<<<1, 256, 0, stream>>>(ws);

    lstm_persistent<<<224, 1024, 0, stream>>>(
        x,
        (const float*)d_in[1],  (const float*)d_in[2],  (const float*)d_in[3],  (const float*)d_in[4],
        (const float*)d_in[5],  (const float*)d_in[6],  (const float*)d_in[7],  (const float*)d_in[8],
        (const float*)d_in[9],  (const float*)d_in[10], (const float*)d_in[11], (const float*)d_in[12],
        ws);

    fc_kernel<<<1, 256, 0, stream>>>(ws, (const float*)d_in[13], (const float*)d_in[14], (float*)d_out);
}